// Round 9
// baseline (291.251 us; speedup 1.0000x reference)
//
#include <hip/hip_runtime.h>

#define S_LEN 2048
#define DMODEL 1024
#define H_CNT 16
#define DK 64
#define BATCH 4

typedef __attribute__((ext_vector_type(8))) short short8;
typedef __attribute__((ext_vector_type(4))) float f32x4;
typedef __attribute__((ext_vector_type(16))) float f32x16;

static __device__ __forceinline__ short f2bf(float f) {
  union { float f; unsigned u; } x; x.f = f;
  unsigned r = x.u + 0x7fffu + ((x.u >> 16) & 1u);
  return (short)(r >> 16);
}

static __device__ __forceinline__ unsigned cvt_pk_bf16(float lo, float hi) {
  unsigned r;
  asm("v_cvt_pk_bf16_f32 %0, %1, %2" : "=v"(r) : "v"(lo), "v"(hi));
  return r;
}

static __device__ __forceinline__ void gl_lds16(const short* g, short* l) {
  __builtin_amdgcn_global_load_lds((const __attribute__((address_space(1))) void*)g,
                                   (__attribute__((address_space(3))) void*)l, 16, 0, 0);
}

// ---------------- cast fp32 -> bf16, 8 elems/thread ----------------
__global__ __launch_bounds__(256) void cast_kernel(const float* __restrict__ src,
                                                   short* __restrict__ dst, int n8) {
  int i = blockIdx.x * 256 + threadIdx.x;
  if (i >= n8) return;
  const float4* s4 = (const float4*)src;
  float4 a = s4[2 * i], b = s4[2 * i + 1];
  short8 o;
  o[0] = f2bf(a.x); o[1] = f2bf(a.y); o[2] = f2bf(a.z); o[3] = f2bf(a.w);
  o[4] = f2bf(b.x); o[5] = f2bf(b.y); o[6] = f2bf(b.z); o[7] = f2bf(b.w);
  ((short8*)dst)[i] = o;
}

// ---------------- GEMM v2 (known-good since r6) ----------------
// 128x64 tile, BK=32, 4 waves, global_load_lds 16B staging, XCD swizzle.
// MODE 0: A=x, B=w. out bf16 -> (B,H,S,dk). bias[col], then *scl.  (Q, K)
// MODE 1: A=w, B=x. out bf16 -> (B,H,dk,S) = V^T. bias[row].       (V)
// MODE 2: A=attn, B=w. out fp32 row-major [M,N]. bias[col].        (final)
// grid MUST be 1024 blocks; MODE1: M=1024,N=8192; else M=8192,N=1024.
template <int MODE>
__global__ __launch_bounds__(256) void gemm_bt(const short* __restrict__ A,
                                               const short* __restrict__ B,
                                               const float* __restrict__ bias,
                                               void* __restrict__ Cout,
                                               int M, int N, int K, float scl) {
  __shared__ short Sab[(128 + 64) * 32];  // As: rows 0..127, Bs: rows 128..191
  const int tid = threadIdx.x;
  const int lane = tid & 63, wid = tid >> 6;
  const int lin = blockIdx.x;
  const int w = (lin & 7) * 128 + (lin >> 3);
  int bx, by;
  if (MODE == 1) { bx = w >> 3; by = w & 7; }
  else           { bx = w & 15; by = w >> 4; }
  const int m0 = by * 128, n0 = bx * 64;
  const int wr = wid * 32;
  const int lrow = lane & 15, lk8 = (lane >> 4) * 8;

  const int l4 = lane >> 2, lc = (lane & 3) * 8;
  const short* gsrc[3];
  short* ldst[3];
#pragma unroll
  for (int i = 0; i < 3; i++) {
    int c = wid * 3 + i;
    ldst[i] = &Sab[c * 512];
    if (c < 8) gsrc[i] = &A[(size_t)(m0 + c * 16 + l4) * K + lc];
    else       gsrc[i] = &B[(size_t)(n0 + (c - 8) * 16 + l4) * K + lc];
  }

  f32x4 acc[2][4] = {};

  for (int k0 = 0; k0 < K; k0 += 32) {
#pragma unroll
    for (int i = 0; i < 3; i++) gl_lds16(gsrc[i] + k0, ldst[i]);
    __syncthreads();
    short8 af[2], bfr[4];
#pragma unroll
    for (int m = 0; m < 2; m++) af[m] = *(const short8*)(&Sab[(wr + m * 16 + lrow) * 32 + lk8]);
#pragma unroll
    for (int n = 0; n < 4; n++) bfr[n] = *(const short8*)(&Sab[(128 + n * 16 + lrow) * 32 + lk8]);
#pragma unroll
    for (int m = 0; m < 2; m++)
#pragma unroll
      for (int n = 0; n < 4; n++)
        acc[m][n] = __builtin_amdgcn_mfma_f32_16x16x32_bf16(af[m], bfr[n], acc[m][n], 0, 0, 0);
    __syncthreads();
  }

  const int g4 = (lane >> 4) * 4;
#pragma unroll
  for (int n = 0; n < 4; n++) {
    const int col = n0 + n * 16 + lrow;
#pragma unroll
    for (int m = 0; m < 2; m++) {
#pragma unroll
      for (int i = 0; i < 4; i++) {
        const int row = m0 + wr + m * 16 + g4 + i;
        float val = acc[m][n][i];
        if (MODE == 0) {
          val = (val + bias[col]) * scl;
          int b = row >> 11, s2 = row & 2047, h = col >> 6, d = col & 63;
          ((short*)Cout)[((size_t)(b * H_CNT + h) * S_LEN + s2) * DK + d] = f2bf(val);
        } else if (MODE == 1) {
          val = val + bias[row];
          int h = row >> 6, d = row & 63, b = col >> 11, s2 = col & 2047;
          ((short*)Cout)[((size_t)(b * H_CNT + h) * DK + d) * S_LEN + s2] = f2bf(val);
        } else {
          val = val + bias[col];
          ((float*)Cout)[(size_t)row * N + col] = val;
        }
      }
    }
  }
}

// ---------------- causal flash attention v6: KVBLK=64, branchless softmax ----
// r8 structure (r2/r6 shell: grid dim3(16,B*H), 256 thr = 4 waves, wave w owns
// q-tile {j,31-j,32+j,63-j}[w]; 64-wide KV iterations, 16 loads + 16 MFMAs +
// one softmax pass per iteration) with the defer-max branch REMOVED:
// unconditional rescale each tile (mr = true running max) and a protective
// fminf(.,0) before exp2 (no-op when everything is correct).
__global__ __launch_bounds__(256, 2) void attn2_kernel(const short* __restrict__ Q,
                                                       const short* __restrict__ Kc,
                                                       const short* __restrict__ Vt,
                                                       short* __restrict__ Oout) {
  const int bh = blockIdx.y;
  const int j = blockIdx.x;
  const int wid = threadIdx.x >> 6, lane = threadIdx.x & 63;
  const int qt = (wid == 0) ? j : (wid == 1) ? (31 - j) : (wid == 2) ? (32 + j) : (63 - j);
  const int q0 = qt * 32;
  const int ql = lane & 31, hl = lane >> 5;

  const short* Qb = Q + (size_t)bh * S_LEN * DK;
  const short* Kb = Kc + (size_t)bh * S_LEN * DK;
  const short* Vb = Vt + (size_t)bh * DK * S_LEN;

  short8 qf[4];
#pragma unroll
  for (int kk = 0; kk < 4; kk++)
    qf[kk] = *(const short8*)(&Qb[(q0 + ql) * DK + kk * 16 + hl * 8]);

  f32x16 oacc[2] = {};
  float mr = -1e30f, lr = 0.f;

  const int nt = qt / 2 + 1;  // 64-wide tiles; covers kv in [0, q0+32)
  for (int t = 0; t < nt; t++) {
    const int kv0 = t * 64;

    // issue ALL loads for this 64-kv tile (16 x 16B in flight)
    short8 kf[2][4];
#pragma unroll
    for (int c = 0; c < 2; c++)
#pragma unroll
      for (int kk = 0; kk < 4; kk++)
        kf[c][kk] = *(const short8*)(&Kb[(kv0 + 32 * c + ql) * DK + kk * 16 + hl * 8]);
    short8 vf[2][2][2];
#pragma unroll
    for (int td = 0; td < 2; td++)
#pragma unroll
      for (int c = 0; c < 2; c++)
#pragma unroll
        for (int k2 = 0; k2 < 2; k2++)
          vf[td][c][k2] =
              *(const short8*)(&Vb[(size_t)(td * 32 + ql) * S_LEN + kv0 + 32 * c + k2 * 16 + hl * 8]);

    // S^T[kv, q] for the two 32-kv sub-tiles
    f32x16 st0 = {}, st1 = {};
#pragma unroll
    for (int kk = 0; kk < 4; kk++)
      st0 = __builtin_amdgcn_mfma_f32_32x32x16_bf16(kf[0][kk], qf[kk], st0, 0, 0, 0);
#pragma unroll
    for (int kk = 0; kk < 4; kk++)
      st1 = __builtin_amdgcn_mfma_f32_32x32x16_bf16(kf[1][kk], qf[kk], st1, 0, 0, 0);

    float p[32];
#pragma unroll
    for (int r = 0; r < 16; r++) { p[r] = st0[r]; p[16 + r] = st1[r]; }

    // wave-uniform masking per sub-tile
#pragma unroll
    for (int c = 0; c < 2; c++) {
      const int base = kv0 + 32 * c;
      if (base == q0) {
#pragma unroll
        for (int r = 0; r < 16; r++) {
          int kvr = (r & 3) + 8 * (r >> 2) + 4 * hl;
          if (kvr > ql) p[16 * c + r] = -1e30f;
        }
      } else if (base > q0) {
#pragma unroll
        for (int r = 0; r < 16; r++) p[16 * c + r] = -1e30f;
      }
    }

    // softmax: row max -> UNCONDITIONAL rescale (branchless, mr = true max)
    float pm = p[0];
#pragma unroll
    for (int r = 1; r < 32; r++) pm = fmaxf(pm, p[r]);
    pm = fmaxf(pm, __shfl_xor(pm, 32, 64));
    const float mnew = fmaxf(mr, pm);
    const float al = __builtin_amdgcn_exp2f(mr - mnew);
    mr = mnew;
    lr *= al;
#pragma unroll
    for (int td = 0; td < 2; td++)
#pragma unroll
      for (int r = 0; r < 16; r++) oacc[td][r] *= al;

    float rs = 0.f;
#pragma unroll
    for (int r = 0; r < 32; r++) {
      p[r] = __builtin_amdgcn_exp2f(fminf(p[r] - mr, 0.f));
      rs += p[r];
    }
    rs += __shfl_xor(rs, 32, 64);
    lr += rs;

    // pack + PV per 32-kv sub-tile (r6-verified construction)
#pragma unroll
    for (int c = 0; c < 2; c++) {
      unsigned wpk[8];
#pragma unroll
      for (int tt = 0; tt < 8; tt++)
        wpk[tt] = cvt_pk_bf16(p[16 * c + 2 * tt], p[16 * c + 2 * tt + 1]);
      union { short8 s; unsigned u[4]; } bf0, bf1;
      {
        unsigned xa = __shfl_xor((int)wpk[2], 32, 64), xb = __shfl_xor((int)wpk[0], 32, 64);
        bf0.u[0] = hl ? xa : wpk[0];
        bf0.u[2] = hl ? wpk[2] : xb;
      }
      {
        unsigned xa = __shfl_xor((int)wpk[3], 32, 64), xb = __shfl_xor((int)wpk[1], 32, 64);
        bf0.u[1] = hl ? xa : wpk[1];
        bf0.u[3] = hl ? wpk[3] : xb;
      }
      {
        unsigned xa = __shfl_xor((int)wpk[6], 32, 64), xb = __shfl_xor((int)wpk[4], 32, 64);
        bf1.u[0] = hl ? xa : wpk[4];
        bf1.u[2] = hl ? wpk[6] : xb;
      }
      {
        unsigned xa = __shfl_xor((int)wpk[7], 32, 64), xb = __shfl_xor((int)wpk[5], 32, 64);
        bf1.u[1] = hl ? xa : wpk[5];
        bf1.u[3] = hl ? wpk[7] : xb;
      }
#pragma unroll
      for (int td = 0; td < 2; td++) {
        oacc[td] = __builtin_amdgcn_mfma_f32_32x32x16_bf16(vf[td][c][0], bf0.s, oacc[td], 0, 0, 0);
        oacc[td] = __builtin_amdgcn_mfma_f32_32x32x16_bf16(vf[td][c][1], bf1.s, oacc[td], 0, 0, 0);
      }
    }
  }

  const float inv = __builtin_amdgcn_rcpf(lr);
  const int b = bh >> 4, h = bh & 15;
  unsigned* ob = (unsigned*)Oout + ((size_t)b * S_LEN + q0 + ql) * (DMODEL / 2) + h * (DK / 2);
#pragma unroll
  for (int td = 0; td < 2; td++)
#pragma unroll
    for (int tt = 0; tt < 8; tt++) {
      unsigned pkv = cvt_pk_bf16(oacc[td][2 * tt] * inv, oacc[td][2 * tt + 1] * inv);
      ob[td * 16 + (tt & 1) + 4 * (tt >> 1) + 2 * hl] = pkv;
    }
}

// ---------------- launcher ----------------
extern "C" void kernel_launch(void* const* d_in, const int* in_sizes, int n_in,
                              void* d_out, int out_size, void* d_ws, size_t ws_size,
                              hipStream_t stream) {
  (void)in_sizes; (void)n_in; (void)out_size; (void)ws_size;
  const float* query = (const float*)d_in[0];
  const float* key_i = (const float*)d_in[1];
  const float* value = (const float*)d_in[2];
  const float* w_q = (const float*)d_in[4];
  const float* b_q = (const float*)d_in[5];
  const float* w_k = (const float*)d_in[6];
  const float* b_k = (const float*)d_in[7];
  const float* w_v = (const float*)d_in[8];
  const float* b_v = (const float*)d_in[9];
  const float* w_o = (const float*)d_in[10];
  const float* b_o = (const float*)d_in[11];

  const size_t XE = (size_t)BATCH * S_LEN * DMODEL;  // 8388608
  const size_t WE = (size_t)DMODEL * DMODEL;         // 1048576

  short* xq = (short*)d_ws;
  short* xk = xq + XE;
  short* xv = xk + XE;
  short* wq = xv + XE;
  short* wk = wq + WE;
  short* wv = wk + WE;
  short* wo = wv + WE;
  short* qb = wo + WE;
  short* kb = qb + XE;
  short* vtb = kb + XE;
  short* attnb = xq;  // reuse: xq dead after Q projection

  const int M = BATCH * S_LEN;  // 8192

  int n8x = (int)(XE / 8), n8w = (int)(WE / 8);
  cast_kernel<<<dim3((n8x + 255) / 256), 256, 0, stream>>>(query, xq, n8x);
  cast_kernel<<<dim3((n8x + 255) / 256), 256, 0, stream>>>(key_i, xk, n8x);
  cast_kernel<<<dim3((n8x + 255) / 256), 256, 0, stream>>>(value, xv, n8x);
  cast_kernel<<<dim3((n8w + 255) / 256), 256, 0, stream>>>(w_q, wq, n8w);
  cast_kernel<<<dim3((n8w + 255) / 256), 256, 0, stream>>>(w_k, wk, n8w);
  cast_kernel<<<dim3((n8w + 255) / 256), 256, 0, stream>>>(w_v, wv, n8w);
  cast_kernel<<<dim3((n8w + 255) / 256), 256, 0, stream>>>(w_o, wo, n8w);

  // Q pre-scaled by 1/sqrt(dk) * log2(e): attention works in exp2 domain
  const float qscale = 0.125f * 1.44269504088896f;

  gemm_bt<0><<<1024, 256, 0, stream>>>(xq, wq, b_q, qb, M, DMODEL, DMODEL, qscale);
  gemm_bt<0><<<1024, 256, 0, stream>>>(xk, wk, b_k, kb, M, DMODEL, DMODEL, 1.f);
  gemm_bt<1><<<1024, 256, 0, stream>>>(wv, xv, b_v, vtb, DMODEL, M, DMODEL, 1.f);

  attn2_kernel<<<dim3(16, BATCH * H_CNT), 256, 0, stream>>>(qb, kb, vtb, attnb);

  gemm_bt<2><<<1024, 256, 0, stream>>>(attnb, wo, b_o, d_out, M, DMODEL, DMODEL, 1.f);
}

// Round 13
// 286.275 us; speedup vs baseline: 1.0174x; 1.0174x over previous
//
#include <hip/hip_runtime.h>

#define S_LEN 2048
#define DMODEL 1024
#define H_CNT 16
#define DK 64
#define BATCH 4

typedef __attribute__((ext_vector_type(8))) short short8;
typedef __attribute__((ext_vector_type(4))) float f32x4;
typedef __attribute__((ext_vector_type(16))) float f32x16;
typedef __attribute__((ext_vector_type(4))) unsigned uint4v;

static __device__ __forceinline__ short f2bf(float f) {
  union { float f; unsigned u; } x; x.f = f;
  unsigned r = x.u + 0x7fffu + ((x.u >> 16) & 1u);
  return (short)(r >> 16);
}

// pure-C pack of two floats into one u32 of 2x bf16 (lo in low half). No asm.
static __device__ __forceinline__ unsigned pack_bf2(float lo, float hi) {
  return (((unsigned)(unsigned short)f2bf(hi)) << 16) | ((unsigned)(unsigned short)f2bf(lo));
}

static __device__ __forceinline__ void gl_lds16(const short* g, short* l) {
  __builtin_amdgcn_global_load_lds((const __attribute__((address_space(1))) void*)g,
                                   (__attribute__((address_space(3))) void*)l, 16, 0, 0);
}

// ---------------- cast fp32 -> bf16, 8 elems/thread ----------------
__global__ __launch_bounds__(256) void cast_kernel(const float* __restrict__ src,
                                                   short* __restrict__ dst, int n8) {
  int i = blockIdx.x * 256 + threadIdx.x;
  if (i >= n8) return;
  const float4* s4 = (const float4*)src;
  float4 a = s4[2 * i], b = s4[2 * i + 1];
  short8 o;
  o[0] = f2bf(a.x); o[1] = f2bf(a.y); o[2] = f2bf(a.z); o[3] = f2bf(a.w);
  o[4] = f2bf(b.x); o[5] = f2bf(b.y); o[6] = f2bf(b.z); o[7] = f2bf(b.w);
  ((short8*)dst)[i] = o;
}

// ---------------- GEMM v3: 128x128 tile, BK=64 (validated r11==r12) ----------
// C[M,N] = A[M,K]*B[N,K]^T (+bias)*scl. 4 waves, each 64x64 out (4x4 16x16 acc).
// MODE 0: A=x, B=w. out bf16 -> (B,H,S,dk). bias[col], *scl.   (Q, K)
// MODE 1: A=w, B=x. out bf16 -> (B,H,dk,S) = V^T. bias[row].   (V)
// MODE 2: A=attn, B=w. out fp32 row-major [M,N]. bias[col].    (final)
// grid MUST be 512 blocks; MODE1: M=1024,N=8192; else M=8192,N=1024.
template <int MODE>
__global__ __launch_bounds__(256) void gemm3(const short* __restrict__ A,
                                             const short* __restrict__ B,
                                             const float* __restrict__ bias,
                                             void* __restrict__ Cout,
                                             int M, int N, int K, float scl) {
  __shared__ short As[128 * 64];
  __shared__ short Bs[128 * 64];
  const int tid = threadIdx.x;
  const int lane = tid & 63, wid = tid >> 6;
  const int lin = blockIdx.x;
  const int w = (lin & 7) * 64 + (lin >> 3);
  int bx, by;
  if (MODE == 1) { bx = w >> 3; by = w & 7; }
  else           { bx = w & 7;  by = w >> 3; }
  const int m0 = by * 128, n0 = bx * 128;
  const int wr = (wid >> 1) * 64, wc = (wid & 1) * 64;
  const int lrow = lane & 15, lk8 = (lane >> 4) * 8;

  const int srow = lane >> 3, scol = (lane & 7) * 8;
  const int arow = m0 + wid * 32 + srow;
  const int brow = n0 + wid * 32 + srow;

  f32x4 acc[4][4] = {};

  for (int k0 = 0; k0 < K; k0 += 64) {
#pragma unroll
    for (int i = 0; i < 4; i++) {
      gl_lds16(&A[(size_t)(arow + i * 8) * K + k0 + scol], &As[(wid * 32 + i * 8) * 64]);
      gl_lds16(&B[(size_t)(brow + i * 8) * K + k0 + scol], &Bs[(wid * 32 + i * 8) * 64]);
    }
    __syncthreads();
    short8 af[4][2], bfr[4][2];
#pragma unroll
    for (int m = 0; m < 4; m++)
#pragma unroll
      for (int kk = 0; kk < 2; kk++)
        af[m][kk] = *(const short8*)(&As[(wr + m * 16 + lrow) * 64 + kk * 32 + lk8]);
#pragma unroll
    for (int n = 0; n < 4; n++)
#pragma unroll
      for (int kk = 0; kk < 2; kk++)
        bfr[n][kk] = *(const short8*)(&Bs[(wc + n * 16 + lrow) * 64 + kk * 32 + lk8]);
#pragma unroll
    for (int kk = 0; kk < 2; kk++)
#pragma unroll
      for (int m = 0; m < 4; m++)
#pragma unroll
        for (int n = 0; n < 4; n++)
          acc[m][n] = __builtin_amdgcn_mfma_f32_16x16x32_bf16(af[m][kk], bfr[n][kk], acc[m][n], 0, 0, 0);
    __syncthreads();
  }

  const int g4 = (lane >> 4) * 4;
#pragma unroll
  for (int n = 0; n < 4; n++) {
    const int col = n0 + wc + n * 16 + lrow;
#pragma unroll
    for (int m = 0; m < 4; m++) {
#pragma unroll
      for (int i = 0; i < 4; i++) {
        const int row = m0 + wr + m * 16 + g4 + i;
        float val = acc[m][n][i];
        if (MODE == 0) {
          val = (val + bias[col]) * scl;
          int b = row >> 11, s2 = row & 2047, h = col >> 6, d = col & 63;
          ((short*)Cout)[((size_t)(b * H_CNT + h) * S_LEN + s2) * DK + d] = f2bf(val);
        } else if (MODE == 1) {
          val = val + bias[row];
          int h = row >> 6, d = row & 63, b = col >> 11, s2 = col & 2047;
          ((short*)Cout)[((size_t)(b * H_CNT + h) * DK + d) * S_LEN + s2] = f2bf(val);
        } else {
          val = val + bias[col];
          ((float*)Cout)[(size_t)row * N + col] = val;
        }
      }
    }
  }
}

// ---------------- causal flash attention v9: UB-free pack ----------------
// r12 body with the P-packing cluster rewritten: NO inline asm, NO union
// type-pun. Pure-C bf16 pack (pack_bf2) + uint ext-vector + bit_cast.
// Natural grid dim3(16, B*H); block 256 = 4 waves; wave w owns q-tile
// {j,31-j,32+j,63-j}[w]. Branchless unconditional rescale + fminf guard.
__global__ __launch_bounds__(256, 4) void attn2_kernel(const short* __restrict__ Q,
                                                       const short* __restrict__ Kc,
                                                       const short* __restrict__ Vt,
                                                       short* __restrict__ Oout) {
  const int bh = blockIdx.y;
  const int j = blockIdx.x;
  const int wid = threadIdx.x >> 6, lane = threadIdx.x & 63;
  const int qt = (wid == 0) ? j : (wid == 1) ? (31 - j) : (wid == 2) ? (32 + j) : (63 - j);
  const int q0 = qt * 32;
  const int ql = lane & 31, hl = lane >> 5;

  const short* Qb = Q + (size_t)bh * S_LEN * DK;
  const short* Kb = Kc + (size_t)bh * S_LEN * DK;
  const short* Vb = Vt + (size_t)bh * DK * S_LEN;

  short8 qf[4];
#pragma unroll
  for (int kk = 0; kk < 4; kk++)
    qf[kk] = *(const short8*)(&Qb[(q0 + ql) * DK + kk * 16 + hl * 8]);

  f32x16 oacc[2] = {};
  float mr = -1e30f, lr = 0.f;

  const int ntiles = qt + 1;
  for (int t = 0; t < ntiles; t++) {
    const int kv0 = t * 32;
    f32x16 st = {};
#pragma unroll
    for (int kk = 0; kk < 4; kk++) {
      short8 kf = *(const short8*)(&Kb[(kv0 + ql) * DK + kk * 16 + hl * 8]);
      st = __builtin_amdgcn_mfma_f32_32x32x16_bf16(kf, qf[kk], st, 0, 0, 0);
    }
    short8 vf[2][2];
#pragma unroll
    for (int td = 0; td < 2; td++)
#pragma unroll
      for (int kk = 0; kk < 2; kk++)
        vf[td][kk] = *(const short8*)(&Vb[(size_t)(td * 32 + ql) * S_LEN + kv0 + kk * 16 + hl * 8]);

    float p[16];
#pragma unroll
    for (int r = 0; r < 16; r++) p[r] = st[r];
    if (t == ntiles - 1) {
#pragma unroll
      for (int r = 0; r < 16; r++) {
        int kvr = (r & 3) + 8 * (r >> 2) + 4 * hl;
        if (kvr > ql) p[r] = -1e30f;
      }
    }
    float pm = p[0];
#pragma unroll
    for (int r = 1; r < 16; r++) pm = fmaxf(pm, p[r]);
    pm = fmaxf(pm, __shfl_xor(pm, 32, 64));
    const float mnew = fmaxf(mr, pm);
    const float al = __builtin_amdgcn_exp2f(mr - mnew);
    mr = mnew;
    lr *= al;
#pragma unroll
    for (int td = 0; td < 2; td++)
#pragma unroll
      for (int r = 0; r < 16; r++) oacc[td][r] *= al;

    float rs = 0.f;
#pragma unroll
    for (int r = 0; r < 16; r++) {
      p[r] = __builtin_amdgcn_exp2f(fminf(p[r] - mr, 0.f));
      rs += p[r];
    }
    rs += __shfl_xor(rs, 32, 64);
    lr += rs;

    // ---- P -> bf16 PV B-fragments: pure C pack, no asm, no union ----
    unsigned wpk[8];
#pragma unroll
    for (int tt = 0; tt < 8; tt++) wpk[tt] = pack_bf2(p[2 * tt], p[2 * tt + 1]);
    uint4v u0, u1;
    {
      unsigned xa = __shfl_xor((int)wpk[2], 32, 64), xb = __shfl_xor((int)wpk[0], 32, 64);
      u0[0] = hl ? xa : wpk[0];
      u0[2] = hl ? wpk[2] : xb;
    }
    {
      unsigned xa = __shfl_xor((int)wpk[3], 32, 64), xb = __shfl_xor((int)wpk[1], 32, 64);
      u0[1] = hl ? xa : wpk[1];
      u0[3] = hl ? wpk[3] : xb;
    }
    {
      unsigned xa = __shfl_xor((int)wpk[6], 32, 64), xb = __shfl_xor((int)wpk[4], 32, 64);
      u1[0] = hl ? xa : wpk[4];
      u1[2] = hl ? wpk[6] : xb;
    }
    {
      unsigned xa = __shfl_xor((int)wpk[7], 32, 64), xb = __shfl_xor((int)wpk[5], 32, 64);
      u1[1] = hl ? xa : wpk[5];
      u1[3] = hl ? wpk[7] : xb;
    }
    const short8 pb0 = __builtin_bit_cast(short8, u0);
    const short8 pb1 = __builtin_bit_cast(short8, u1);

#pragma unroll
    for (int td = 0; td < 2; td++) {
      oacc[td] = __builtin_amdgcn_mfma_f32_32x32x16_bf16(vf[td][0], pb0, oacc[td], 0, 0, 0);
      oacc[td] = __builtin_amdgcn_mfma_f32_32x32x16_bf16(vf[td][1], pb1, oacc[td], 0, 0, 0);
    }
  }

  const float inv = __builtin_amdgcn_rcpf(lr);
  const int b = bh >> 4, h = bh & 15;
  unsigned* ob = (unsigned*)Oout + ((size_t)b * S_LEN + q0 + ql) * (DMODEL / 2) + h * (DK / 2);
#pragma unroll
  for (int td = 0; td < 2; td++)
#pragma unroll
    for (int tt = 0; tt < 8; tt++) {
      unsigned pkv = pack_bf2(oacc[td][2 * tt] * inv, oacc[td][2 * tt + 1] * inv);
      ob[td * 16 + (tt & 1) + 4 * (tt >> 1) + 2 * hl] = pkv;
    }
}

// ---------------- launcher ----------------
extern "C" void kernel_launch(void* const* d_in, const int* in_sizes, int n_in,
                              void* d_out, int out_size, void* d_ws, size_t ws_size,
                              hipStream_t stream) {
  (void)in_sizes; (void)n_in; (void)out_size; (void)ws_size;
  const float* query = (const float*)d_in[0];
  const float* key_i = (const float*)d_in[1];
  const float* value = (const float*)d_in[2];
  const float* w_q = (const float*)d_in[4];
  const float* b_q = (const float*)d_in[5];
  const float* w_k = (const float*)d_in[6];
  const float* b_k = (const float*)d_in[7];
  const float* w_v = (const float*)d_in[8];
  const float* b_v = (const float*)d_in[9];
  const float* w_o = (const float*)d_in[10];
  const float* b_o = (const float*)d_in[11];

  const size_t XE = (size_t)BATCH * S_LEN * DMODEL;  // 8388608
  const size_t WE = (size_t)DMODEL * DMODEL;         // 1048576

  short* xq = (short*)d_ws;
  short* xk = xq + XE;
  short* xv = xk + XE;
  short* wq = xv + XE;
  short* wk = wq + WE;
  short* wv = wk + WE;
  short* wo = wv + WE;
  short* qb = wo + WE;
  short* kb = qb + XE;
  short* vtb = kb + XE;
  short* attnb = xq;  // reuse: xq dead after Q projection

  const int M = BATCH * S_LEN;  // 8192

  int n8x = (int)(XE / 8), n8w = (int)(WE / 8);
  cast_kernel<<<dim3((n8x + 255) / 256), 256, 0, stream>>>(query, xq, n8x);
  cast_kernel<<<dim3((n8x + 255) / 256), 256, 0, stream>>>(key_i, xk, n8x);
  cast_kernel<<<dim3((n8x + 255) / 256), 256, 0, stream>>>(value, xv, n8x);
  cast_kernel<<<dim3((n8w + 255) / 256), 256, 0, stream>>>(w_q, wq, n8w);
  cast_kernel<<<dim3((n8w + 255) / 256), 256, 0, stream>>>(w_k, wk, n8w);
  cast_kernel<<<dim3((n8w + 255) / 256), 256, 0, stream>>>(w_v, wv, n8w);
  cast_kernel<<<dim3((n8w + 255) / 256), 256, 0, stream>>>(w_o, wo, n8w);

  // Q pre-scaled by 1/sqrt(dk) * log2(e): attention works in exp2 domain
  const float qscale = 0.125f * 1.44269504088896f;

  gemm3<0><<<512, 256, 0, stream>>>(xq, wq, b_q, qb, M, DMODEL, DMODEL, qscale);
  gemm3<0><<<512, 256, 0, stream>>>(xk, wk, b_k, kb, M, DMODEL, DMODEL, 1.f);
  gemm3<1><<<512, 256, 0, stream>>>(wv, xv, b_v, vtb, DMODEL, M, DMODEL, 1.f);

  attn2_kernel<<<dim3(16, BATCH * H_CNT), 256, 0, stream>>>(qb, kb, vtb, attnb);

  gemm3<2><<<512, 256, 0, stream>>>(attnb, wo, b_o, d_out, M, DMODEL, DMODEL, 1.f);
}

// Round 14
// 280.790 us; speedup vs baseline: 1.0373x; 1.0195x over previous
//
#include <hip/hip_runtime.h>

#define S_LEN 2048
#define DMODEL 1024
#define H_CNT 16
#define DK 64
#define BATCH 4

typedef __attribute__((ext_vector_type(8))) short short8;
typedef __attribute__((ext_vector_type(4))) float f32x4;
typedef __attribute__((ext_vector_type(16))) float f32x16;
typedef __attribute__((ext_vector_type(4))) unsigned uint4v;

static __device__ __forceinline__ short f2bf(float f) {
  union { float f; unsigned u; } x; x.f = f;
  unsigned r = x.u + 0x7fffu + ((x.u >> 16) & 1u);
  return (short)(r >> 16);
}

// pure-C pack of two floats into one u32 of 2x bf16 (lo in low half). No asm.
static __device__ __forceinline__ unsigned pack_bf2(float lo, float hi) {
  return (((unsigned)(unsigned short)f2bf(hi)) << 16) | ((unsigned)(unsigned short)f2bf(lo));
}

static __device__ __forceinline__ void gl_lds16(const short* g, short* l) {
  __builtin_amdgcn_global_load_lds((const __attribute__((address_space(1))) void*)g,
                                   (__attribute__((address_space(3))) void*)l, 16, 0, 0);
}

// ---------------- cast fp32 -> bf16, 8 elems/thread ----------------
__global__ __launch_bounds__(256) void cast_kernel(const float* __restrict__ src,
                                                   short* __restrict__ dst, int n8) {
  int i = blockIdx.x * 256 + threadIdx.x;
  if (i >= n8) return;
  const float4* s4 = (const float4*)src;
  float4 a = s4[2 * i], b = s4[2 * i + 1];
  short8 o;
  o[0] = f2bf(a.x); o[1] = f2bf(a.y); o[2] = f2bf(a.z); o[3] = f2bf(a.w);
  o[4] = f2bf(b.x); o[5] = f2bf(b.y); o[6] = f2bf(b.z); o[7] = f2bf(b.w);
  ((short8*)dst)[i] = o;
}

// ---------------- GEMM v3: 128x128 tile, BK=64 (validated r11==r12) ----------
// C[M,N] = A[M,K]*B[N,K]^T (+bias)*scl. 4 waves, each 64x64 out (4x4 16x16 acc).
// MODE 0: A=x, B=w. out bf16 -> (B,H,S,dk). bias[col], *scl.   (Q, K)
// MODE 1: A=w, B=x. out bf16 -> (B,H,dk,S) = V^T. bias[row].   (V)
// MODE 2: A=attn, B=w. out fp32 row-major [M,N]. bias[col].    (final)
// grid MUST be 512 blocks; MODE1: M=1024,N=8192; else M=8192,N=1024.
template <int MODE>
__global__ __launch_bounds__(256) void gemm3(const short* __restrict__ A,
                                             const short* __restrict__ B,
                                             const float* __restrict__ bias,
                                             void* __restrict__ Cout,
                                             int M, int N, int K, float scl) {
  __shared__ short As[128 * 64];
  __shared__ short Bs[128 * 64];
  const int tid = threadIdx.x;
  const int lane = tid & 63, wid = tid >> 6;
  const int lin = blockIdx.x;
  const int w = (lin & 7) * 64 + (lin >> 3);
  int bx, by;
  if (MODE == 1) { bx = w >> 3; by = w & 7; }
  else           { bx = w & 7;  by = w >> 3; }
  const int m0 = by * 128, n0 = bx * 128;
  const int wr = (wid >> 1) * 64, wc = (wid & 1) * 64;
  const int lrow = lane & 15, lk8 = (lane >> 4) * 8;

  const int srow = lane >> 3, scol = (lane & 7) * 8;
  const int arow = m0 + wid * 32 + srow;
  const int brow = n0 + wid * 32 + srow;

  f32x4 acc[4][4] = {};

  for (int k0 = 0; k0 < K; k0 += 64) {
#pragma unroll
    for (int i = 0; i < 4; i++) {
      gl_lds16(&A[(size_t)(arow + i * 8) * K + k0 + scol], &As[(wid * 32 + i * 8) * 64]);
      gl_lds16(&B[(size_t)(brow + i * 8) * K + k0 + scol], &Bs[(wid * 32 + i * 8) * 64]);
    }
    __syncthreads();
    short8 af[4][2], bfr[4][2];
#pragma unroll
    for (int m = 0; m < 4; m++)
#pragma unroll
      for (int kk = 0; kk < 2; kk++)
        af[m][kk] = *(const short8*)(&As[(wr + m * 16 + lrow) * 64 + kk * 32 + lk8]);
#pragma unroll
    for (int n = 0; n < 4; n++)
#pragma unroll
      for (int kk = 0; kk < 2; kk++)
        bfr[n][kk] = *(const short8*)(&Bs[(wc + n * 16 + lrow) * 64 + kk * 32 + lk8]);
#pragma unroll
    for (int kk = 0; kk < 2; kk++)
#pragma unroll
      for (int m = 0; m < 4; m++)
#pragma unroll
        for (int n = 0; n < 4; n++)
          acc[m][n] = __builtin_amdgcn_mfma_f32_16x16x32_bf16(af[m][kk], bfr[n][kk], acc[m][n], 0, 0, 0);
    __syncthreads();
  }

  const int g4 = (lane >> 4) * 4;
#pragma unroll
  for (int n = 0; n < 4; n++) {
    const int col = n0 + wc + n * 16 + lrow;
#pragma unroll
    for (int m = 0; m < 4; m++) {
#pragma unroll
      for (int i = 0; i < 4; i++) {
        const int row = m0 + wr + m * 16 + g4 + i;
        float val = acc[m][n][i];
        if (MODE == 0) {
          val = (val + bias[col]) * scl;
          int b = row >> 11, s2 = row & 2047, h = col >> 6, d = col & 63;
          ((short*)Cout)[((size_t)(b * H_CNT + h) * S_LEN + s2) * DK + d] = f2bf(val);
        } else if (MODE == 1) {
          val = val + bias[row];
          int h = row >> 6, d = row & 63, b = col >> 11, s2 = col & 2047;
          ((short*)Cout)[((size_t)(b * H_CNT + h) * DK + d) * S_LEN + s2] = f2bf(val);
        } else {
          val = val + bias[col];
          ((float*)Cout)[(size_t)row * N + col] = val;
        }
      }
    }
  }
}

// ---------------- causal flash attention v10: L2-local grid ----------------
// r13's validated UB-free body, single change: grid dims swapped to
// dim3(64,16) (bh = blockIdx.x, j = blockIdx.y). Linear block id = bh + 64*j,
// 64 % 8 == 0 -> all 16 q-blocks of head bh land on XCD bh%8 under
// round-robin dispatch: 8 heads x 512KB K/V = 4MB = one XCD L2.
// block 256 = 4 waves; wave w owns q-tile {j,31-j,32+j,63-j}[w].
__global__ __launch_bounds__(256, 4) void attn2_kernel(const short* __restrict__ Q,
                                                       const short* __restrict__ Kc,
                                                       const short* __restrict__ Vt,
                                                       short* __restrict__ Oout) {
  const int bh = blockIdx.x;
  const int j = blockIdx.y;
  const int wid = threadIdx.x >> 6, lane = threadIdx.x & 63;
  const int qt = (wid == 0) ? j : (wid == 1) ? (31 - j) : (wid == 2) ? (32 + j) : (63 - j);
  const int q0 = qt * 32;
  const int ql = lane & 31, hl = lane >> 5;

  const short* Qb = Q + (size_t)bh * S_LEN * DK;
  const short* Kb = Kc + (size_t)bh * S_LEN * DK;
  const short* Vb = Vt + (size_t)bh * DK * S_LEN;

  short8 qf[4];
#pragma unroll
  for (int kk = 0; kk < 4; kk++)
    qf[kk] = *(const short8*)(&Qb[(q0 + ql) * DK + kk * 16 + hl * 8]);

  f32x16 oacc[2] = {};
  float mr = -1e30f, lr = 0.f;

  const int ntiles = qt + 1;
  for (int t = 0; t < ntiles; t++) {
    const int kv0 = t * 32;
    f32x16 st = {};
#pragma unroll
    for (int kk = 0; kk < 4; kk++) {
      short8 kf = *(const short8*)(&Kb[(kv0 + ql) * DK + kk * 16 + hl * 8]);
      st = __builtin_amdgcn_mfma_f32_32x32x16_bf16(kf, qf[kk], st, 0, 0, 0);
    }
    short8 vf[2][2];
#pragma unroll
    for (int td = 0; td < 2; td++)
#pragma unroll
      for (int kk = 0; kk < 2; kk++)
        vf[td][kk] = *(const short8*)(&Vb[(size_t)(td * 32 + ql) * S_LEN + kv0 + kk * 16 + hl * 8]);

    float p[16];
#pragma unroll
    for (int r = 0; r < 16; r++) p[r] = st[r];
    if (t == ntiles - 1) {
#pragma unroll
      for (int r = 0; r < 16; r++) {
        int kvr = (r & 3) + 8 * (r >> 2) + 4 * hl;
        if (kvr > ql) p[r] = -1e30f;
      }
    }
    float pm = p[0];
#pragma unroll
    for (int r = 1; r < 16; r++) pm = fmaxf(pm, p[r]);
    pm = fmaxf(pm, __shfl_xor(pm, 32, 64));
    const float mnew = fmaxf(mr, pm);
    const float al = __builtin_amdgcn_exp2f(mr - mnew);
    mr = mnew;
    lr *= al;
#pragma unroll
    for (int td = 0; td < 2; td++)
#pragma unroll
      for (int r = 0; r < 16; r++) oacc[td][r] *= al;

    float rs = 0.f;
#pragma unroll
    for (int r = 0; r < 16; r++) {
      p[r] = __builtin_amdgcn_exp2f(fminf(p[r] - mr, 0.f));
      rs += p[r];
    }
    rs += __shfl_xor(rs, 32, 64);
    lr += rs;

    // ---- P -> bf16 PV B-fragments: pure C pack, no asm, no union ----
    unsigned wpk[8];
#pragma unroll
    for (int tt = 0; tt < 8; tt++) wpk[tt] = pack_bf2(p[2 * tt], p[2 * tt + 1]);
    uint4v u0, u1;
    {
      unsigned xa = __shfl_xor((int)wpk[2], 32, 64), xb = __shfl_xor((int)wpk[0], 32, 64);
      u0[0] = hl ? xa : wpk[0];
      u0[2] = hl ? wpk[2] : xb;
    }
    {
      unsigned xa = __shfl_xor((int)wpk[3], 32, 64), xb = __shfl_xor((int)wpk[1], 32, 64);
      u0[1] = hl ? xa : wpk[1];
      u0[3] = hl ? wpk[3] : xb;
    }
    {
      unsigned xa = __shfl_xor((int)wpk[6], 32, 64), xb = __shfl_xor((int)wpk[4], 32, 64);
      u1[0] = hl ? xa : wpk[4];
      u1[2] = hl ? wpk[6] : xb;
    }
    {
      unsigned xa = __shfl_xor((int)wpk[7], 32, 64), xb = __shfl_xor((int)wpk[5], 32, 64);
      u1[1] = hl ? xa : wpk[5];
      u1[3] = hl ? wpk[7] : xb;
    }
    const short8 pb0 = __builtin_bit_cast(short8, u0);
    const short8 pb1 = __builtin_bit_cast(short8, u1);

#pragma unroll
    for (int td = 0; td < 2; td++) {
      oacc[td] = __builtin_amdgcn_mfma_f32_32x32x16_bf16(vf[td][0], pb0, oacc[td], 0, 0, 0);
      oacc[td] = __builtin_amdgcn_mfma_f32_32x32x16_bf16(vf[td][1], pb1, oacc[td], 0, 0, 0);
    }
  }

  const float inv = __builtin_amdgcn_rcpf(lr);
  const int b = bh >> 4, h = bh & 15;
  unsigned* ob = (unsigned*)Oout + ((size_t)b * S_LEN + q0 + ql) * (DMODEL / 2) + h * (DK / 2);
#pragma unroll
  for (int td = 0; td < 2; td++)
#pragma unroll
    for (int tt = 0; tt < 8; tt++) {
      unsigned pkv = pack_bf2(oacc[td][2 * tt] * inv, oacc[td][2 * tt + 1] * inv);
      ob[td * 16 + (tt & 1) + 4 * (tt >> 1) + 2 * hl] = pkv;
    }
}

// ---------------- launcher ----------------
extern "C" void kernel_launch(void* const* d_in, const int* in_sizes, int n_in,
                              void* d_out, int out_size, void* d_ws, size_t ws_size,
                              hipStream_t stream) {
  (void)in_sizes; (void)n_in; (void)out_size; (void)ws_size;
  const float* query = (const float*)d_in[0];
  const float* key_i = (const float*)d_in[1];
  const float* value = (const float*)d_in[2];
  const float* w_q = (const float*)d_in[4];
  const float* b_q = (const float*)d_in[5];
  const float* w_k = (const float*)d_in[6];
  const float* b_k = (const float*)d_in[7];
  const float* w_v = (const float*)d_in[8];
  const float* b_v = (const float*)d_in[9];
  const float* w_o = (const float*)d_in[10];
  const float* b_o = (const float*)d_in[11];

  const size_t XE = (size_t)BATCH * S_LEN * DMODEL;  // 8388608
  const size_t WE = (size_t)DMODEL * DMODEL;         // 1048576

  short* xq = (short*)d_ws;
  short* xk = xq + XE;
  short* xv = xk + XE;
  short* wq = xv + XE;
  short* wk = wq + WE;
  short* wv = wk + WE;
  short* wo = wv + WE;
  short* qb = wo + WE;
  short* kb = qb + XE;
  short* vtb = kb + XE;
  short* attnb = xq;  // reuse: xq dead after Q projection

  const int M = BATCH * S_LEN;  // 8192

  int n8x = (int)(XE / 8), n8w = (int)(WE / 8);
  cast_kernel<<<dim3((n8x + 255) / 256), 256, 0, stream>>>(query, xq, n8x);
  cast_kernel<<<dim3((n8x + 255) / 256), 256, 0, stream>>>(key_i, xk, n8x);
  cast_kernel<<<dim3((n8x + 255) / 256), 256, 0, stream>>>(value, xv, n8x);
  cast_kernel<<<dim3((n8w + 255) / 256), 256, 0, stream>>>(w_q, wq, n8w);
  cast_kernel<<<dim3((n8w + 255) / 256), 256, 0, stream>>>(w_k, wk, n8w);
  cast_kernel<<<dim3((n8w + 255) / 256), 256, 0, stream>>>(w_v, wv, n8w);
  cast_kernel<<<dim3((n8w + 255) / 256), 256, 0, stream>>>(w_o, wo, n8w);

  // Q pre-scaled by 1/sqrt(dk) * log2(e): attention works in exp2 domain
  const float qscale = 0.125f * 1.44269504088896f;

  gemm3<0><<<512, 256, 0, stream>>>(xq, wq, b_q, qb, M, DMODEL, DMODEL, qscale);
  gemm3<0><<<512, 256, 0, stream>>>(xk, wk, b_k, kb, M, DMODEL, DMODEL, 1.f);
  gemm3<1><<<512, 256, 0, stream>>>(wv, xv, b_v, vtb, DMODEL, M, DMODEL, 1.f);

  attn2_kernel<<<dim3(BATCH * H_CNT, 16), 256, 0, stream>>>(qb, kb, vtb, attnb);

  gemm3<2><<<512, 256, 0, stream>>>(attnb, wo, b_o, d_out, M, DMODEL, DMODEL, 1.f);
}